// Round 1
// baseline (658.194 us; speedup 1.0000x reference)
//
#include <hip/hip_runtime.h>
#include <cstdint>
#include <cstddef>

#define DFEAT 512

typedef __attribute__((ext_vector_type(8))) short bf16x8;
typedef __attribute__((ext_vector_type(4))) float f32x4;

// float -> bf16 round-to-nearest-even (finite inputs)
__device__ __forceinline__ unsigned short f2bf(float f) {
  unsigned u = __float_as_uint(f);
  u = u + 0x7fffu + ((u >> 16) & 1u);
  return (unsigned short)(u >> 16);
}

__global__ void k_init(int* __restrict__ deg, int* __restrict__ fill, int N) {
  int i = blockIdx.x * blockDim.x + threadIdx.x;
  if (i < N) { deg[i] = 1; fill[i] = 0; }  // deg starts at 1 for the self-loop
}

__global__ void k_count(const int* __restrict__ dst, int* __restrict__ deg, int E) {
  int i = blockIdx.x * blockDim.x + threadIdx.x;
  if (i < E) atomicAdd(&deg[dst[i]], 1);
}

__global__ void k_dinv(const int* __restrict__ deg, float* __restrict__ dinv, int N) {
  int i = blockIdx.x * blockDim.x + threadIdx.x;
  if (i < N) dinv[i] = rsqrtf((float)deg[i]);  // deg >= 1 always
}

// single-block exclusive scan of deg -> rowStart[0..N]
__global__ void k_scan(const int* __restrict__ deg, int* __restrict__ rowStart, int N) {
  const int t = threadIdx.x;
  const int C = (N + 1023) / 1024;
  int lo = t * C;
  int hi = lo + C; if (hi > N) hi = N; if (lo > N) lo = N;
  int sum = 0;
  for (int i = lo; i < hi; ++i) sum += deg[i];
  __shared__ int sm[1024];
  sm[t] = sum;
  __syncthreads();
  for (int d = 1; d < 1024; d <<= 1) {
    int v = (t >= d) ? sm[t - d] : 0;
    __syncthreads();
    sm[t] += v;
    __syncthreads();
  }
  int off = sm[t] - sum;  // exclusive prefix for this chunk
  for (int i = lo; i < hi; ++i) { rowStart[i] = off; off += deg[i]; }
  if (t == 1023) rowStart[N] = sm[1023];
}

__global__ void k_fill(const int* __restrict__ src, const int* __restrict__ dst,
                       const int* __restrict__ rowStart, int* __restrict__ fill,
                       int* __restrict__ col, int E, int N) {
  int i = blockIdx.x * blockDim.x + threadIdx.x;
  if (i >= E + N) return;
  int d, s;
  if (i < E) { d = dst[i]; s = src[i]; }
  else       { d = i - E; s = d; }        // self-loop
  int pos = rowStart[d] + atomicAdd(&fill[d], 1);
  col[pos] = s;
}

// Wt[n][k] = bf16(W[k][n])  (W row-major K x N)
__global__ void k_wt(const float* __restrict__ W, unsigned short* __restrict__ Wt) {
  int i = blockIdx.x * blockDim.x + threadIdx.x;  // i = k*512 + n, coalesced read
  int k = i >> 9, n = i & 511;
  Wt[(size_t)n * DFEAT + k] = f2bf(W[i]);
}

// Y[n][:] = bf16( dinv[n] * sum_{p in row n} dinv[col[p]] * X[col[p]][:] )
__global__ void k_aggregate(const float* __restrict__ X, const int* __restrict__ col,
                            const int* __restrict__ rowStart, const float* __restrict__ dinv,
                            unsigned short* __restrict__ Y) {
  int n = blockIdx.x;
  int t = threadIdx.x;        // 0..255, handles cols 2t, 2t+1
  int s = rowStart[n], e = rowStart[n + 1];
  int c0 = 2 * t;
  float ax = 0.f, ay = 0.f;
  for (int p = s; p < e; ++p) {
    int c = col[p];
    float w = dinv[c];
    const float2 xv = *reinterpret_cast<const float2*>(&X[(size_t)c * DFEAT + c0]);
    ax = fmaf(w, xv.x, ax);
    ay = fmaf(w, xv.y, ay);
  }
  float scale = dinv[n];
  unsigned packed = (unsigned)f2bf(ax * scale) | ((unsigned)f2bf(ay * scale) << 16);
  *reinterpret_cast<unsigned*>(&Y[(size_t)n * DFEAT + c0]) = packed;
}

// out[M x 512] = LeakyReLU( Y(bf16) @ W + b ), Wt is W transposed (bf16, [n][k])
// block = 256 threads = 4 waves; each wave computes a 64(M) x 64(N) tile from
// 4x4 mfma_f32_16x16x32_bf16 tiles. grid = (Mpad/256, 512/64).
__global__ __launch_bounds__(256) void k_gemm(const unsigned short* __restrict__ Y,
                                              const unsigned short* __restrict__ Wt,
                                              const float* __restrict__ b,
                                              float* __restrict__ out, int M) {
  const int lane = threadIdx.x & 63;
  const int wave = threadIdx.x >> 6;
  const int l16 = lane & 15;
  const int quad = lane >> 4;
  const int m0 = blockIdx.x * 256 + wave * 64;
  const int n0 = blockIdx.y * 64;

  f32x4 acc[4][4];
#pragma unroll
  for (int mi = 0; mi < 4; ++mi)
#pragma unroll
    for (int ni = 0; ni < 4; ++ni) { f32x4 z = {0.f, 0.f, 0.f, 0.f}; acc[mi][ni] = z; }

  // A: lane holds A[m = m0+16*mi+l16][k = kk + quad*8 + j], j=0..7 (16B contiguous)
  // B: lane holds B[k = kk + quad*8 + j][n = n0+16*ni+l16] via Wt rows
  const unsigned short* Ybase = Y + (size_t)(m0 + l16) * DFEAT + quad * 8;
  const unsigned short* Wbase = Wt + (size_t)(n0 + l16) * DFEAT + quad * 8;

  for (int kk = 0; kk < DFEAT; kk += 32) {
    bf16x8 av[4], bv[4];
#pragma unroll
    for (int mi = 0; mi < 4; ++mi)
      av[mi] = *reinterpret_cast<const bf16x8*>(Ybase + (size_t)mi * 16 * DFEAT + kk);
#pragma unroll
    for (int ni = 0; ni < 4; ++ni)
      bv[ni] = *reinterpret_cast<const bf16x8*>(Wbase + (size_t)ni * 16 * DFEAT + kk);
#pragma unroll
    for (int mi = 0; mi < 4; ++mi)
#pragma unroll
      for (int ni = 0; ni < 4; ++ni)
        acc[mi][ni] = __builtin_amdgcn_mfma_f32_16x16x32_bf16(av[mi], bv[ni], acc[mi][ni], 0, 0, 0);
  }

  float bvals[4];
#pragma unroll
  for (int ni = 0; ni < 4; ++ni) bvals[ni] = b[n0 + 16 * ni + l16];

  // C/D layout: col = lane&15, row = quad*4 + r
#pragma unroll
  for (int mi = 0; mi < 4; ++mi) {
#pragma unroll
    for (int r = 0; r < 4; ++r) {
      int row = m0 + 16 * mi + quad * 4 + r;
      if (row < M) {
#pragma unroll
        for (int ni = 0; ni < 4; ++ni) {
          float v = acc[mi][ni][r] + bvals[ni];
          v = (v >= 0.f) ? v : 0.01f * v;
          out[(size_t)row * DFEAT + n0 + 16 * ni + l16] = v;
        }
      }
    }
  }
}

extern "C" void kernel_launch(void* const* d_in, const int* in_sizes, int n_in,
                              void* d_out, int out_size, void* d_ws, size_t ws_size,
                              hipStream_t stream) {
  const float* X = (const float*)d_in[0];
  const float* W = (const float*)d_in[1];
  const float* b = (const float*)d_in[2];
  const int* ei  = (const int*)d_in[3];
  const int D = DFEAT;
  const int N = in_sizes[0] / D;   // 50000
  const int E = in_sizes[3] / 2;   // 800000
  const int* src = ei;
  const int* dst = ei + E;
  float* out = (float*)d_out;

  // carve workspace (256B-aligned slices)
  uintptr_t p = (uintptr_t)d_ws;
  auto carve = [&](size_t bytes) -> void* {
    uintptr_t r = p;
    p += (bytes + 255) & ~(size_t)255;
    return (void*)r;
  };
  int*   deg      = (int*)carve(sizeof(int) * (size_t)N);
  int*   fill     = (int*)carve(sizeof(int) * (size_t)N);
  int*   rowStart = (int*)carve(sizeof(int) * (size_t)(N + 1));
  float* dinv     = (float*)carve(sizeof(float) * (size_t)N);
  int*   col      = (int*)carve(sizeof(int) * (size_t)(E + N));
  unsigned short* Wt = (unsigned short*)carve(sizeof(unsigned short) * (size_t)D * D);
  const int Mpad = (N + 255) & ~255;   // 50176
  unsigned short* Y  = (unsigned short*)carve(sizeof(unsigned short) * (size_t)Mpad * D);

  hipLaunchKernelGGL(k_init,  dim3((N + 255) / 256), dim3(256), 0, stream, deg, fill, N);
  hipLaunchKernelGGL(k_count, dim3((E + 255) / 256), dim3(256), 0, stream, dst, deg, E);
  hipLaunchKernelGGL(k_dinv,  dim3((N + 255) / 256), dim3(256), 0, stream, deg, dinv, N);
  hipLaunchKernelGGL(k_scan,  dim3(1), dim3(1024), 0, stream, deg, rowStart, N);
  hipLaunchKernelGGL(k_fill,  dim3((E + N + 255) / 256), dim3(256), 0, stream,
                     src, dst, rowStart, fill, col, E, N);
  hipLaunchKernelGGL(k_wt,    dim3((D * D) / 256), dim3(256), 0, stream, W, Wt);
  hipLaunchKernelGGL(k_aggregate, dim3(N), dim3(256), 0, stream, X, col, rowStart, dinv, Y);
  hipLaunchKernelGGL(k_gemm,  dim3(Mpad / 256, D / 64), dim3(256), 0, stream, Y, Wt, b, out, N);
}

// Round 2
// 518.163 us; speedup vs baseline: 1.2702x; 1.2702x over previous
//
#include <hip/hip_runtime.h>
#include <cstdint>
#include <cstddef>

#define DFEAT 512
#define BM 128
#define BN 128
#define BK 32

typedef __attribute__((ext_vector_type(8))) short bf16x8;
typedef __attribute__((ext_vector_type(4))) float f32x4;

#define GLOBAL_AS __attribute__((address_space(1)))
#define LDS_AS __attribute__((address_space(3)))

// float -> bf16 round-to-nearest-even (finite inputs)
__device__ __forceinline__ unsigned short f2bf(float f) {
  unsigned u = __float_as_uint(f);
  u = u + 0x7fffu + ((u >> 16) & 1u);
  return (unsigned short)(u >> 16);
}

__device__ __forceinline__ float bf2f_lo(unsigned u) { return __uint_as_float(u << 16); }
__device__ __forceinline__ float bf2f_hi(unsigned u) { return __uint_as_float(u & 0xffff0000u); }

__device__ __forceinline__ void gl_lds16(const void* g, void* l) {
  __builtin_amdgcn_global_load_lds((const GLOBAL_AS unsigned int*)g,
                                   (LDS_AS unsigned int*)l, 16, 0, 0);
}

__global__ void k_init(int* __restrict__ deg, int* __restrict__ fill, int N) {
  int i = blockIdx.x * blockDim.x + threadIdx.x;
  if (i < N) { deg[i] = 1; fill[i] = 0; }  // deg starts at 1 for the self-loop
}

__global__ void k_count(const int* __restrict__ dst, int* __restrict__ deg, int E) {
  int i = blockIdx.x * blockDim.x + threadIdx.x;
  if (i < E) atomicAdd(&deg[dst[i]], 1);
}

__global__ void k_dinv(const int* __restrict__ deg, float* __restrict__ dinv, int N) {
  int i = blockIdx.x * blockDim.x + threadIdx.x;
  if (i < N) dinv[i] = rsqrtf((float)deg[i]);  // deg >= 1 always
}

// single-block exclusive scan of deg -> rowStart[0..N]
__global__ void k_scan(const int* __restrict__ deg, int* __restrict__ rowStart, int N) {
  const int t = threadIdx.x;
  const int C = (N + 1023) / 1024;
  int lo = t * C;
  int hi = lo + C; if (hi > N) hi = N; if (lo > N) lo = N;
  int sum = 0;
  for (int i = lo; i < hi; ++i) sum += deg[i];
  __shared__ int sm[1024];
  sm[t] = sum;
  __syncthreads();
  for (int d = 1; d < 1024; d <<= 1) {
    int v = (t >= d) ? sm[t - d] : 0;
    __syncthreads();
    sm[t] += v;
    __syncthreads();
  }
  int off = sm[t] - sum;  // exclusive prefix for this chunk
  for (int i = lo; i < hi; ++i) { rowStart[i] = off; off += deg[i]; }
  if (t == 1023) rowStart[N] = sm[1023];
}

__global__ void k_fill(const int* __restrict__ src, const int* __restrict__ dst,
                       const int* __restrict__ rowStart, int* __restrict__ fill,
                       int* __restrict__ col, int E, int N) {
  int i = blockIdx.x * blockDim.x + threadIdx.x;
  if (i >= E + N) return;
  int d, s;
  if (i < E) { d = dst[i]; s = src[i]; }
  else       { d = i - E; s = d; }        // self-loop
  int pos = rowStart[d] + atomicAdd(&fill[d], 1);
  col[pos] = s;
}

// Wt[n][k] = bf16(W[k][n])  (W row-major K x N)
__global__ void k_wt(const float* __restrict__ W, unsigned short* __restrict__ Wt) {
  int i = blockIdx.x * blockDim.x + threadIdx.x;  // i = k*512 + n, coalesced read
  int k = i >> 9, n = i & 511;
  Wt[(size_t)n * DFEAT + k] = f2bf(W[i]);
}

// Xb[i] = bf16(X[i]) — thread handles 8 elements (2x float4 in, 1x uint4 out)
__global__ void k_xb(const float* __restrict__ X, unsigned short* __restrict__ Xb, int total8) {
  int i = blockIdx.x * blockDim.x + threadIdx.x;
  if (i >= total8) return;
  const float4 a = *reinterpret_cast<const float4*>(X + (size_t)i * 8);
  const float4 c = *reinterpret_cast<const float4*>(X + (size_t)i * 8 + 4);
  uint4 o;
  o.x = (unsigned)f2bf(a.x) | ((unsigned)f2bf(a.y) << 16);
  o.y = (unsigned)f2bf(a.z) | ((unsigned)f2bf(a.w) << 16);
  o.z = (unsigned)f2bf(c.x) | ((unsigned)f2bf(c.y) << 16);
  o.w = (unsigned)f2bf(c.z) | ((unsigned)f2bf(c.w) << 16);
  *reinterpret_cast<uint4*>(Xb + (size_t)i * 8) = o;
}

// One wave per dst row. Lane handles features [lane*8, lane*8+8) via 16B loads.
// Y[row][:] = bf16( dinv[row] * sum_{p} dinv[col[p]] * Xb[col[p]][:] ); rows >= N zeroed.
__global__ __launch_bounds__(256) void k_aggregate(const unsigned short* __restrict__ Xb,
                                                   const int* __restrict__ col,
                                                   const int* __restrict__ rowStart,
                                                   const float* __restrict__ dinv,
                                                   unsigned short* __restrict__ Y, int N) {
  const int row = blockIdx.x * 4 + (threadIdx.x >> 6);
  const int lane = threadIdx.x & 63;
  float acc[8] = {0.f, 0.f, 0.f, 0.f, 0.f, 0.f, 0.f, 0.f};
  if (row < N) {
    const int s = rowStart[row], e = rowStart[row + 1];
    for (int p = s; p < e; ++p) {
      const int c = col[p];
      const float w = dinv[c];
      const uint4 v = *reinterpret_cast<const uint4*>(Xb + (size_t)c * DFEAT + lane * 8);
      acc[0] = fmaf(w, bf2f_lo(v.x), acc[0]);
      acc[1] = fmaf(w, bf2f_hi(v.x), acc[1]);
      acc[2] = fmaf(w, bf2f_lo(v.y), acc[2]);
      acc[3] = fmaf(w, bf2f_hi(v.y), acc[3]);
      acc[4] = fmaf(w, bf2f_lo(v.z), acc[4]);
      acc[5] = fmaf(w, bf2f_hi(v.z), acc[5]);
      acc[6] = fmaf(w, bf2f_lo(v.w), acc[6]);
      acc[7] = fmaf(w, bf2f_hi(v.w), acc[7]);
    }
    const float sc = dinv[row];
#pragma unroll
    for (int j = 0; j < 8; ++j) acc[j] *= sc;
  }
  uint4 o;
  o.x = (unsigned)f2bf(acc[0]) | ((unsigned)f2bf(acc[1]) << 16);
  o.y = (unsigned)f2bf(acc[2]) | ((unsigned)f2bf(acc[3]) << 16);
  o.z = (unsigned)f2bf(acc[4]) | ((unsigned)f2bf(acc[5]) << 16);
  o.w = (unsigned)f2bf(acc[6]) | ((unsigned)f2bf(acc[7]) << 16);
  *reinterpret_cast<uint4*>(Y + (size_t)row * DFEAT + lane * 8) = o;
}

// out[M x 512] = LeakyReLU( Y(bf16) @ W + b ). m97-style: 128x128 tile, BK=32,
// global_load_lds width-16 staging, 4 waves x (64x64 via 4x4 mfma 16x16x32).
__global__ __launch_bounds__(256) void k_gemm(const unsigned short* __restrict__ Y,
                                              const unsigned short* __restrict__ Wt,
                                              const float* __restrict__ bias,
                                              float* __restrict__ out, int M) {
  __shared__ unsigned short As[BM * BK];  // [m][k], 8 KB
  __shared__ unsigned short Bs[BN * BK];  // [n][k], 8 KB
  const int tid = threadIdx.x;
  const int lane = tid & 63;
  const int wave = tid >> 6;
  const int l16 = lane & 15;
  const int quad = lane >> 4;
  const int wm = (wave >> 1) * 64;
  const int wn = (wave & 1) * 64;
  const int m0 = blockIdx.x * BM;
  const int n0 = blockIdx.y * BN;

  f32x4 acc[4][4];
#pragma unroll
  for (int mi = 0; mi < 4; ++mi)
#pragma unroll
    for (int ni = 0; ni < 4; ++ni) { f32x4 z = {0.f, 0.f, 0.f, 0.f}; acc[mi][ni] = z; }

  // staging: chunk ci in [0,512) = 16B; LDS off = ci*16B; row = ci>>2, k-quad = ci&3.
  // wave-uniform base + lane*16 per global_load_lds constraint.
  const int ci0 = wave * 64 + lane;
  const int ci1 = 256 + ci0;
  const int ra0 = ci0 >> 2, ka0 = (ci0 & 3) * 8;
  const int ra1 = ci1 >> 2, ka1 = (ci1 & 3) * 8;

  const unsigned short* Ag0 = Y + (size_t)(m0 + ra0) * DFEAT + ka0;
  const unsigned short* Ag1 = Y + (size_t)(m0 + ra1) * DFEAT + ka1;
  const unsigned short* Bg0 = Wt + (size_t)(n0 + ra0) * DFEAT + ka0;
  const unsigned short* Bg1 = Wt + (size_t)(n0 + ra1) * DFEAT + ka1;
  unsigned short* La0 = As + ci0 * 8;
  unsigned short* La1 = As + ci1 * 8;
  unsigned short* Lb0 = Bs + ci0 * 8;
  unsigned short* Lb1 = Bs + ci1 * 8;

  const unsigned short* AsRd = As + (wm + l16) * BK + quad * 8;
  const unsigned short* BsRd = Bs + (wn + l16) * BK + quad * 8;

  for (int kk = 0; kk < DFEAT; kk += BK) {
    gl_lds16(Ag0 + kk, La0);
    gl_lds16(Ag1 + kk, La1);
    gl_lds16(Bg0 + kk, Lb0);
    gl_lds16(Bg1 + kk, Lb1);
    __syncthreads();  // drains vmcnt (global_load_lds) per m97 semantics
    bf16x8 av[4], bv[4];
#pragma unroll
    for (int mi = 0; mi < 4; ++mi)
      av[mi] = *reinterpret_cast<const bf16x8*>(AsRd + mi * 16 * BK);
#pragma unroll
    for (int ni = 0; ni < 4; ++ni)
      bv[ni] = *reinterpret_cast<const bf16x8*>(BsRd + ni * 16 * BK);
#pragma unroll
    for (int mi = 0; mi < 4; ++mi)
#pragma unroll
      for (int ni = 0; ni < 4; ++ni)
        acc[mi][ni] = __builtin_amdgcn_mfma_f32_16x16x32_bf16(av[mi], bv[ni], acc[mi][ni], 0, 0, 0);
    __syncthreads();  // protect LDS before next stage
  }

  float bvals[4];
#pragma unroll
  for (int ni = 0; ni < 4; ++ni) bvals[ni] = bias[n0 + wn + 16 * ni + l16];

  // C/D layout: col = lane&15, row = quad*4 + r
#pragma unroll
  for (int mi = 0; mi < 4; ++mi) {
#pragma unroll
    for (int r = 0; r < 4; ++r) {
      int row = m0 + wm + 16 * mi + quad * 4 + r;
      if (row < M) {
#pragma unroll
        for (int ni = 0; ni < 4; ++ni) {
          float v = acc[mi][ni][r] + bvals[ni];
          v = (v >= 0.f) ? v : 0.01f * v;
          out[(size_t)row * DFEAT + n0 + wn + 16 * ni + l16] = v;
        }
      }
    }
  }
}

extern "C" void kernel_launch(void* const* d_in, const int* in_sizes, int n_in,
                              void* d_out, int out_size, void* d_ws, size_t ws_size,
                              hipStream_t stream) {
  const float* X = (const float*)d_in[0];
  const float* W = (const float*)d_in[1];
  const float* b = (const float*)d_in[2];
  const int* ei  = (const int*)d_in[3];
  const int D = DFEAT;
  const int N = in_sizes[0] / D;   // 50000
  const int E = in_sizes[3] / 2;   // 800000
  const int* src = ei;
  const int* dst = ei + E;
  float* out = (float*)d_out;

  // carve workspace (256B-aligned slices)
  uintptr_t p = (uintptr_t)d_ws;
  auto carve = [&](size_t bytes) -> void* {
    uintptr_t r = p;
    p += (bytes + 255) & ~(size_t)255;
    return (void*)r;
  };
  int*   deg      = (int*)carve(sizeof(int) * (size_t)N);
  int*   fill     = (int*)carve(sizeof(int) * (size_t)N);
  int*   rowStart = (int*)carve(sizeof(int) * (size_t)(N + 1));
  float* dinv     = (float*)carve(sizeof(float) * (size_t)N);
  int*   col      = (int*)carve(sizeof(int) * (size_t)(E + N));
  unsigned short* Wt = (unsigned short*)carve(sizeof(unsigned short) * (size_t)D * D);
  const int Mtiles = (N + BM - 1) / BM;     // 391
  const int Mpad = Mtiles * BM;             // 50048
  unsigned short* Y  = (unsigned short*)carve(sizeof(unsigned short) * (size_t)Mpad * D);

  // Xb (bf16 X) lives in d_out: 51.2 MB needed, 102.4 MB available; dead before k_gemm writes.
  unsigned short* Xb = (unsigned short*)d_out;

  hipLaunchKernelGGL(k_init,  dim3((N + 255) / 256), dim3(256), 0, stream, deg, fill, N);
  hipLaunchKernelGGL(k_count, dim3((E + 255) / 256), dim3(256), 0, stream, dst, deg, E);
  hipLaunchKernelGGL(k_dinv,  dim3((N + 255) / 256), dim3(256), 0, stream, deg, dinv, N);
  hipLaunchKernelGGL(k_scan,  dim3(1), dim3(1024), 0, stream, deg, rowStart, N);
  hipLaunchKernelGGL(k_fill,  dim3((E + N + 255) / 256), dim3(256), 0, stream,
                     src, dst, rowStart, fill, col, E, N);
  hipLaunchKernelGGL(k_wt,    dim3((D * D) / 256), dim3(256), 0, stream, W, Wt);
  hipLaunchKernelGGL(k_xb,    dim3((N * D / 8 + 255) / 256), dim3(256), 0, stream,
                     X, Xb, N * D / 8);
  hipLaunchKernelGGL(k_aggregate, dim3(Mpad / 4), dim3(256), 0, stream,
                     Xb, col, rowStart, dinv, Y, N);
  hipLaunchKernelGGL(k_gemm,  dim3(Mtiles, D / BN), dim3(256), 0, stream, Y, Wt, b, out, N);
}

// Round 3
// 510.122 us; speedup vs baseline: 1.2903x; 1.0158x over previous
//
#include <hip/hip_runtime.h>
#include <cstdint>
#include <cstddef>

#define DFEAT 512
#define BM 128
#define BN 128
#define BK 32

typedef __attribute__((ext_vector_type(8))) short bf16x8;
typedef __attribute__((ext_vector_type(4))) float f32x4;

#define GLOBAL_AS __attribute__((address_space(1)))
#define LDS_AS __attribute__((address_space(3)))

// float -> bf16 round-to-nearest-even (finite inputs)
__device__ __forceinline__ unsigned short f2bf(float f) {
  unsigned u = __float_as_uint(f);
  u = u + 0x7fffu + ((u >> 16) & 1u);
  return (unsigned short)(u >> 16);
}

__device__ __forceinline__ float bf2f_lo(unsigned u) { return __uint_as_float(u << 16); }
__device__ __forceinline__ float bf2f_hi(unsigned u) { return __uint_as_float(u & 0xffff0000u); }

__device__ __forceinline__ void gl_lds16(const void* g, void* l) {
  __builtin_amdgcn_global_load_lds((const GLOBAL_AS unsigned int*)g,
                                   (LDS_AS unsigned int*)l, 16, 0, 0);
}

__global__ void k_init(int* __restrict__ deg, int* __restrict__ fill, int N) {
  int i = blockIdx.x * blockDim.x + threadIdx.x;
  if (i < N) { deg[i] = 1; fill[i] = 0; }  // deg starts at 1 for the self-loop
}

__global__ void k_count(const int* __restrict__ dst, int* __restrict__ deg, int E) {
  int i = blockIdx.x * blockDim.x + threadIdx.x;
  if (i < E) atomicAdd(&deg[dst[i]], 1);
}

__global__ void k_dinv(const int* __restrict__ deg, float* __restrict__ dinv, int N) {
  int i = blockIdx.x * blockDim.x + threadIdx.x;
  if (i < N) dinv[i] = rsqrtf((float)deg[i]);  // deg >= 1 always
}

// single-block exclusive scan of deg -> rowStart[0..N]
__global__ void k_scan(const int* __restrict__ deg, int* __restrict__ rowStart, int N) {
  const int t = threadIdx.x;
  const int C = (N + 1023) / 1024;
  int lo = t * C;
  int hi = lo + C; if (hi > N) hi = N; if (lo > N) lo = N;
  int sum = 0;
  for (int i = lo; i < hi; ++i) sum += deg[i];
  __shared__ int sm[1024];
  sm[t] = sum;
  __syncthreads();
  for (int d = 1; d < 1024; d <<= 1) {
    int v = (t >= d) ? sm[t - d] : 0;
    __syncthreads();
    sm[t] += v;
    __syncthreads();
  }
  int off = sm[t] - sum;  // exclusive prefix for this chunk
  for (int i = lo; i < hi; ++i) { rowStart[i] = off; off += deg[i]; }
  if (t == 1023) rowStart[N] = sm[1023];
}

// cw[pos] = { src, dinv[src] } — fuses the per-edge dinv gather into CSR build
// (dinv is 200 KB, L2-resident here; removes one dependent-load level from k_aggregate)
__global__ void k_fill(const int* __restrict__ src, const int* __restrict__ dst,
                       const int* __restrict__ rowStart, int* __restrict__ fill,
                       int2* __restrict__ cw, const float* __restrict__ dinv, int E, int N) {
  int i = blockIdx.x * blockDim.x + threadIdx.x;
  if (i >= E + N) return;
  int d, s;
  if (i < E) { d = dst[i]; s = src[i]; }
  else       { d = i - E; s = d; }        // self-loop
  int pos = rowStart[d] + atomicAdd(&fill[d], 1);
  int2 q; q.x = s; q.y = __float_as_int(dinv[s]);
  cw[pos] = q;
}

// Wt[n][k] = bf16(W[k][n])  (W row-major K x N)
__global__ void k_wt(const float* __restrict__ W, unsigned short* __restrict__ Wt) {
  int i = blockIdx.x * blockDim.x + threadIdx.x;  // i = k*512 + n, coalesced read
  int k = i >> 9, n = i & 511;
  Wt[(size_t)n * DFEAT + k] = f2bf(W[i]);
}

// Xb[i] = bf16(X[i]) — thread handles 8 elements (2x float4 in, 1x uint4 out)
__global__ void k_xb(const float* __restrict__ X, unsigned short* __restrict__ Xb, int total8) {
  int i = blockIdx.x * blockDim.x + threadIdx.x;
  if (i >= total8) return;
  const float4 a = *reinterpret_cast<const float4*>(X + (size_t)i * 8);
  const float4 c = *reinterpret_cast<const float4*>(X + (size_t)i * 8 + 4);
  uint4 o;
  o.x = (unsigned)f2bf(a.x) | ((unsigned)f2bf(a.y) << 16);
  o.y = (unsigned)f2bf(a.z) | ((unsigned)f2bf(a.w) << 16);
  o.z = (unsigned)f2bf(c.x) | ((unsigned)f2bf(c.y) << 16);
  o.w = (unsigned)f2bf(c.z) | ((unsigned)f2bf(c.w) << 16);
  *reinterpret_cast<uint4*>(Xb + (size_t)i * 8) = o;
}

// One wave per dst row; lane handles features [lane*8, lane*8+8).
// Edge loop batched x4: 4 independent cw loads then 4 independent 1KB gathers
// in flight per wave (MLP x4) — the loop was latency-bound, not BW-bound.
__global__ __launch_bounds__(256) void k_aggregate(const unsigned short* __restrict__ Xb,
                                                   const int2* __restrict__ cw,
                                                   const int* __restrict__ rowStart,
                                                   const float* __restrict__ dinv,
                                                   unsigned short* __restrict__ Y, int N) {
  const int row = blockIdx.x * 4 + (threadIdx.x >> 6);
  const int lane = threadIdx.x & 63;
  float acc[8] = {0.f, 0.f, 0.f, 0.f, 0.f, 0.f, 0.f, 0.f};
  if (row < N) {
    const int s = rowStart[row], e = rowStart[row + 1];
    int p = s;
    for (; p + 4 <= e; p += 4) {
      const int2 q0 = cw[p + 0];
      const int2 q1 = cw[p + 1];
      const int2 q2 = cw[p + 2];
      const int2 q3 = cw[p + 3];
      const uint4 v0 = *reinterpret_cast<const uint4*>(Xb + (size_t)q0.x * DFEAT + lane * 8);
      const uint4 v1 = *reinterpret_cast<const uint4*>(Xb + (size_t)q1.x * DFEAT + lane * 8);
      const uint4 v2 = *reinterpret_cast<const uint4*>(Xb + (size_t)q2.x * DFEAT + lane * 8);
      const uint4 v3 = *reinterpret_cast<const uint4*>(Xb + (size_t)q3.x * DFEAT + lane * 8);
      const float w0 = __int_as_float(q0.y), w1 = __int_as_float(q1.y);
      const float w2 = __int_as_float(q2.y), w3 = __int_as_float(q3.y);
      acc[0] = fmaf(w0, bf2f_lo(v0.x), acc[0]); acc[1] = fmaf(w0, bf2f_hi(v0.x), acc[1]);
      acc[2] = fmaf(w0, bf2f_lo(v0.y), acc[2]); acc[3] = fmaf(w0, bf2f_hi(v0.y), acc[3]);
      acc[4] = fmaf(w0, bf2f_lo(v0.z), acc[4]); acc[5] = fmaf(w0, bf2f_hi(v0.z), acc[5]);
      acc[6] = fmaf(w0, bf2f_lo(v0.w), acc[6]); acc[7] = fmaf(w0, bf2f_hi(v0.w), acc[7]);
      acc[0] = fmaf(w1, bf2f_lo(v1.x), acc[0]); acc[1] = fmaf(w1, bf2f_hi(v1.x), acc[1]);
      acc[2] = fmaf(w1, bf2f_lo(v1.y), acc[2]); acc[3] = fmaf(w1, bf2f_hi(v1.y), acc[3]);
      acc[4] = fmaf(w1, bf2f_lo(v1.z), acc[4]); acc[5] = fmaf(w1, bf2f_hi(v1.z), acc[5]);
      acc[6] = fmaf(w1, bf2f_lo(v1.w), acc[6]); acc[7] = fmaf(w1, bf2f_hi(v1.w), acc[7]);
      acc[0] = fmaf(w2, bf2f_lo(v2.x), acc[0]); acc[1] = fmaf(w2, bf2f_hi(v2.x), acc[1]);
      acc[2] = fmaf(w2, bf2f_lo(v2.y), acc[2]); acc[3] = fmaf(w2, bf2f_hi(v2.y), acc[3]);
      acc[4] = fmaf(w2, bf2f_lo(v2.z), acc[4]); acc[5] = fmaf(w2, bf2f_hi(v2.z), acc[5]);
      acc[6] = fmaf(w2, bf2f_lo(v2.w), acc[6]); acc[7] = fmaf(w2, bf2f_hi(v2.w), acc[7]);
      acc[0] = fmaf(w3, bf2f_lo(v3.x), acc[0]); acc[1] = fmaf(w3, bf2f_hi(v3.x), acc[1]);
      acc[2] = fmaf(w3, bf2f_lo(v3.y), acc[2]); acc[3] = fmaf(w3, bf2f_hi(v3.y), acc[3]);
      acc[4] = fmaf(w3, bf2f_lo(v3.z), acc[4]); acc[5] = fmaf(w3, bf2f_hi(v3.z), acc[5]);
      acc[6] = fmaf(w3, bf2f_lo(v3.w), acc[6]); acc[7] = fmaf(w3, bf2f_hi(v3.w), acc[7]);
    }
    for (; p < e; ++p) {
      const int2 q = cw[p];
      const float w = __int_as_float(q.y);
      const uint4 v = *reinterpret_cast<const uint4*>(Xb + (size_t)q.x * DFEAT + lane * 8);
      acc[0] = fmaf(w, bf2f_lo(v.x), acc[0]); acc[1] = fmaf(w, bf2f_hi(v.x), acc[1]);
      acc[2] = fmaf(w, bf2f_lo(v.y), acc[2]); acc[3] = fmaf(w, bf2f_hi(v.y), acc[3]);
      acc[4] = fmaf(w, bf2f_lo(v.z), acc[4]); acc[5] = fmaf(w, bf2f_hi(v.z), acc[5]);
      acc[6] = fmaf(w, bf2f_lo(v.w), acc[6]); acc[7] = fmaf(w, bf2f_hi(v.w), acc[7]);
    }
    const float sc = dinv[row];
#pragma unroll
    for (int j = 0; j < 8; ++j) acc[j] *= sc;
  }
  uint4 o;
  o.x = (unsigned)f2bf(acc[0]) | ((unsigned)f2bf(acc[1]) << 16);
  o.y = (unsigned)f2bf(acc[2]) | ((unsigned)f2bf(acc[3]) << 16);
  o.z = (unsigned)f2bf(acc[4]) | ((unsigned)f2bf(acc[5]) << 16);
  o.w = (unsigned)f2bf(acc[6]) | ((unsigned)f2bf(acc[7]) << 16);
  *reinterpret_cast<uint4*>(Y + (size_t)row * DFEAT + lane * 8) = o;
}

// out[M x 512] = LeakyReLU( Y(bf16) @ W + b ). 128x128 tile, BK=32,
// global_load_lds width-16 staging, 4 waves x (64x64 via 4x4 mfma 16x16x32).
// LDS chunk mapping swizzled (k-quad rotated by row>>1) so ds_read_b128 lands
// 2-way per bank (free) instead of 8-way (2.9x, m136).
__global__ __launch_bounds__(256) void k_gemm(const unsigned short* __restrict__ Y,
                                              const unsigned short* __restrict__ Wt,
                                              const float* __restrict__ bias,
                                              float* __restrict__ out, int M) {
  __shared__ unsigned short As[BM * BK];  // 8 KB
  __shared__ unsigned short Bs[BN * BK];  // 8 KB
  const int tid = threadIdx.x;
  const int lane = tid & 63;
  const int wave = tid >> 6;
  const int l16 = lane & 15;
  const int quad = lane >> 4;
  const int wm = (wave >> 1) * 64;
  const int wn = (wave & 1) * 64;
  const int m0 = blockIdx.x * BM;
  const int n0 = blockIdx.y * BN;

  f32x4 acc[4][4];
#pragma unroll
  for (int mi = 0; mi < 4; ++mi)
#pragma unroll
    for (int ni = 0; ni < 4; ++ni) { f32x4 z = {0.f, 0.f, 0.f, 0.f}; acc[mi][ni] = z; }

  // staging: LDS slot ci (16B units) holds global chunk (row=ci>>2, kq=((ci&3)-(row>>1))&3)
  const int ci0 = wave * 64 + lane;
  const int ci1 = 256 + ci0;
  const int ra0 = ci0 >> 2, ka0 = (((ci0 & 3) - (ra0 >> 1)) & 3) * 8;
  const int ra1 = ci1 >> 2, ka1 = (((ci1 & 3) - (ra1 >> 1)) & 3) * 8;

  const unsigned short* Ag0 = Y + (size_t)(m0 + ra0) * DFEAT + ka0;
  const unsigned short* Ag1 = Y + (size_t)(m0 + ra1) * DFEAT + ka1;
  const unsigned short* Bg0 = Wt + (size_t)(n0 + ra0) * DFEAT + ka0;
  const unsigned short* Bg1 = Wt + (size_t)(n0 + ra1) * DFEAT + ka1;
  unsigned short* La0 = As + ci0 * 8;
  unsigned short* La1 = As + ci1 * 8;
  unsigned short* Lb0 = Bs + ci0 * 8;
  unsigned short* Lb1 = Bs + ci1 * 8;

  // read side: fragment (row, kq=quad) lives at slot row*4 + ((quad + (row>>1)) & 3)
  const int rotA = (quad + ((wm + l16) >> 1)) & 3;   // same for all mi (16*mi/2 % 4 == 0)
  const int rotB = (quad + ((wn + l16) >> 1)) & 3;
  const unsigned short* AsRd = As + (wm + l16) * BK + rotA * 8;
  const unsigned short* BsRd = Bs + (wn + l16) * BK + rotB * 8;

  for (int kk = 0; kk < DFEAT; kk += BK) {
    gl_lds16(Ag0 + kk, La0);
    gl_lds16(Ag1 + kk, La1);
    gl_lds16(Bg0 + kk, Lb0);
    gl_lds16(Bg1 + kk, Lb1);
    __syncthreads();  // drains vmcnt (global_load_lds) per m97 semantics
    bf16x8 av[4], bv[4];
#pragma unroll
    for (int mi = 0; mi < 4; ++mi)
      av[mi] = *reinterpret_cast<const bf16x8*>(AsRd + mi * 16 * BK);
#pragma unroll
    for (int ni = 0; ni < 4; ++ni)
      bv[ni] = *reinterpret_cast<const bf16x8*>(BsRd + ni * 16 * BK);
#pragma unroll
    for (int mi = 0; mi < 4; ++mi)
#pragma unroll
      for (int ni = 0; ni < 4; ++ni)
        acc[mi][ni] = __builtin_amdgcn_mfma_f32_16x16x32_bf16(av[mi], bv[ni], acc[mi][ni], 0, 0, 0);
    __syncthreads();  // protect LDS before next stage
  }

  float bvals[4];
#pragma unroll
  for (int ni = 0; ni < 4; ++ni) bvals[ni] = bias[n0 + wn + 16 * ni + l16];

  // C/D layout: col = lane&15, row = quad*4 + r
#pragma unroll
  for (int mi = 0; mi < 4; ++mi) {
#pragma unroll
    for (int r = 0; r < 4; ++r) {
      int row = m0 + wm + 16 * mi + quad * 4 + r;
      if (row < M) {
#pragma unroll
        for (int ni = 0; ni < 4; ++ni) {
          float v = acc[mi][ni][r] + bvals[ni];
          v = (v >= 0.f) ? v : 0.01f * v;
          out[(size_t)row * DFEAT + n0 + wn + 16 * ni + l16] = v;
        }
      }
    }
  }
}

extern "C" void kernel_launch(void* const* d_in, const int* in_sizes, int n_in,
                              void* d_out, int out_size, void* d_ws, size_t ws_size,
                              hipStream_t stream) {
  const float* X = (const float*)d_in[0];
  const float* W = (const float*)d_in[1];
  const float* b = (const float*)d_in[2];
  const int* ei  = (const int*)d_in[3];
  const int D = DFEAT;
  const int N = in_sizes[0] / D;   // 50000
  const int E = in_sizes[3] / 2;   // 800000
  const int* src = ei;
  const int* dst = ei + E;
  float* out = (float*)d_out;

  // carve workspace (256B-aligned slices)
  uintptr_t p = (uintptr_t)d_ws;
  auto carve = [&](size_t bytes) -> void* {
    uintptr_t r = p;
    p += (bytes + 255) & ~(size_t)255;
    return (void*)r;
  };
  int*   deg      = (int*)carve(sizeof(int) * (size_t)N);
  int*   fill     = (int*)carve(sizeof(int) * (size_t)N);
  int*   rowStart = (int*)carve(sizeof(int) * (size_t)(N + 1));
  float* dinv     = (float*)carve(sizeof(float) * (size_t)N);
  int2*  cw       = (int2*)carve(sizeof(int2) * (size_t)(E + N));
  unsigned short* Wt = (unsigned short*)carve(sizeof(unsigned short) * (size_t)D * D);
  const int Mtiles = (N + BM - 1) / BM;     // 391
  const int Mpad = Mtiles * BM;             // 50048
  unsigned short* Y  = (unsigned short*)carve(sizeof(unsigned short) * (size_t)Mpad * D);

  // Xb (bf16 X) lives in d_out: 51.2 MB needed, 102.4 MB available; dead before k_gemm writes.
  unsigned short* Xb = (unsigned short*)d_out;

  hipLaunchKernelGGL(k_init,  dim3((N + 255) / 256), dim3(256), 0, stream, deg, fill, N);
  hipLaunchKernelGGL(k_count, dim3((E + 255) / 256), dim3(256), 0, stream, dst, deg, E);
  hipLaunchKernelGGL(k_dinv,  dim3((N + 255) / 256), dim3(256), 0, stream, deg, dinv, N);
  hipLaunchKernelGGL(k_scan,  dim3(1), dim3(1024), 0, stream, deg, rowStart, N);
  hipLaunchKernelGGL(k_fill,  dim3((E + N + 255) / 256), dim3(256), 0, stream,
                     src, dst, rowStart, fill, cw, dinv, E, N);
  hipLaunchKernelGGL(k_wt,    dim3((D * D) / 256), dim3(256), 0, stream, W, Wt);
  hipLaunchKernelGGL(k_xb,    dim3((N * D / 8 + 255) / 256), dim3(256), 0, stream,
                     X, Xb, N * D / 8);
  hipLaunchKernelGGL(k_aggregate, dim3(Mpad / 4), dim3(256), 0, stream,
                     Xb, cw, rowStart, dinv, Y, N);
  hipLaunchKernelGGL(k_gemm,  dim3(Mtiles, D / BN), dim3(256), 0, stream, Y, Wt, b, out, N);
}